// Round 4
// baseline (78.662 us; speedup 1.0000x reference)
//
#include <hip/hip_runtime.h>
#include <math.h>

// GCDD fused, register-pipeline version.
// out = u + div( phi(G)*ux, phi(G)*uy ); 3x3 Sobel cross-correlations with zero
// padding at EVERY conv stage (intermediates forced to 0 outside the domain).
//
// Only u lives in LDS. Each thread owns a 4-wide x 8-tall output strip and
// computes ux/uy -> P,Q -> divergence as a rolling row pipeline in registers:
//   u row jr (su)  ->  ux/uy row e=jr-2  ->  P,Q row m=e-2  ->  out row o=m-2.
// P,Q are never materialized: each P/Q row is immediately reduced to
//   dP[c] = P[c+2]-P[c],  eQ[c] = Q[c]+2Q[c+1]+Q[c+2]
// and out row o = u + (dP[o]+2dP[o+1]+dP[o+2]) + (eQ[o+2]-eQ[o]).
//
// Tile: 128 wide (32 strips) x 64 tall (8 bands x 8 rows), 256 threads.
// su[r][c]: gy = ty0 + r - 3 (r=0..69), gx = tx0 + c - 4 (c=0..135).

#define TW 128
#define TH 64
#define NT 256
#define SUH 70
#define SUW 136

struct Smem { float su[SUH][SUW]; };

template<bool EDGE>
__device__ __forceinline__ void compute_strip(
    const Smem& s, int tid, int tx0, int ty0,
    float* __restrict__ oc, int H, int W)
{
    const int strip = tid & 31;
    const int band  = tid >> 5;
    const int c0 = strip * 4;   // tile out col base
    const int r0 = band * 8;    // tile out row base
    const long obase = (long)(ty0 + r0) * W + (tx0 + c0);

    float uw[3][12];
    float xw[3][8], yw[3][8];
    float dP[3][4], eQ[3][4];

    #pragma unroll
    for (int jr = 0; jr < 14; ++jr) {
        {   // u row jr: su row r0+jr, su cols c0..c0+11 (tile cols c0-4..c0+7)
            float* w = uw[jr % 3];
            *(float4*)&w[0] = *(const float4*)&s.su[r0 + jr][c0];
            *(float4*)&w[4] = *(const float4*)&s.su[r0 + jr][c0 + 4];
            *(float4*)&w[8] = *(const float4*)&s.su[r0 + jr][c0 + 8];
        }
        if (jr < 2) continue;
        const int e = jr - 2;   // ux/uy row: gy = ty0 + r0 - 2 + e
        {
            const float* t = uw[(jr - 2) % 3];
            const float* m = uw[(jr - 1) % 3];
            const float* b = uw[jr % 3];
            float* xr = xw[e % 3];
            float* yr = yw[e % 3];
            bool rowin = true;
            if (EDGE) {
                const int gy = ty0 + r0 - 2 + e;
                rowin = (unsigned)gy < (unsigned)H;
            }
            #pragma unroll
            for (int c = 0; c < 8; ++c) {   // ux col: tile c0-2+c, uses uw[c+1..c+3]
                float A = t[c+1], B = t[c+2], C = t[c+3];
                float D = m[c+1],             E = m[c+3];
                float F = b[c+1], Gg = b[c+2], Hh = b[c+3];
                float x = (C - A) + 2.f*(E - D) + (Hh - F);       // SOBEL_X
                float y = (F + 2.f*Gg + Hh) - (A + 2.f*B + C);    // SOBEL_Y
                if (EDGE) {
                    const int gx = tx0 + c0 - 2 + c;
                    const bool in = rowin & ((unsigned)gx < (unsigned)W);
                    x = in ? x : 0.f;
                    y = in ? y : 0.f;
                }
                xr[c] = x; yr[c] = y;
            }
        }
        if (e < 2) continue;
        const int mI = e - 2;   // P,Q row: gy = ty0 + r0 - 1 + mI
        {
            const float* xt = xw[(e - 2) % 3];
            const float* xm = xw[(e - 1) % 3];
            const float* xb = xw[e % 3];
            const float* yt = yw[(e - 2) % 3];
            const float* ym = yw[(e - 1) % 3];
            const float* yb = yw[e % 3];
            bool rowin = true;
            if (EDGE) {
                const int gy = ty0 + r0 - 1 + mI;
                rowin = (unsigned)gy < (unsigned)H;
            }
            float P[6], Q[6];
            #pragma unroll
            for (int c = 0; c < 6; ++c) {   // P col: tile c0-1+c, uses xw[c..c+2]
                float xc = xm[c+1], yc = ym[c+1];
                float uxx = (xt[c+2]-xt[c]) + 2.f*(xm[c+2]-xm[c]) + (xb[c+2]-xb[c]);
                float uxy = (xb[c] + 2.f*xb[c+1] + xb[c+2])
                          - (xt[c] + 2.f*xt[c+1] + xt[c+2]);
                float uyy = (yb[c] + 2.f*yb[c+1] + yb[c+2])
                          - (yt[c] + 2.f*yt[c+1] + yt[c+2]);
                float den = 1.f + xc*xc + yc*yc;
                float Gv = (uxx*uyy - uxy*uxy)
                         * __builtin_amdgcn_rcpf(den*den + 1e-6f);
                float phi = __expf(-fabsf(Gv));
                float p = phi * xc, q = phi * yc;
                if (EDGE) {
                    const int gx = tx0 + c0 - 1 + c;
                    const bool in = rowin & ((unsigned)gx < (unsigned)W);
                    p = in ? p : 0.f;
                    q = in ? q : 0.f;
                }
                P[c] = p; Q[c] = q;
            }
            float* dp = dP[mI % 3];
            float* eq = eQ[mI % 3];
            #pragma unroll
            for (int c = 0; c < 4; ++c) {
                dp[c] = P[c+2] - P[c];
                eq[c] = Q[c] + 2.f*Q[c+1] + Q[c+2];
            }
        }
        if (mI < 2) continue;
        const int o = mI - 2;   // out row: gy = ty0 + r0 + o
        {
            const float* d0 = dP[(mI - 2) % 3];
            const float* d1 = dP[(mI - 1) % 3];
            const float* d2 = dP[mI % 3];
            const float* e0 = eQ[(mI - 2) % 3];
            const float* e2 = eQ[mI % 3];
            const float4 ur = *(const float4*)&s.su[r0 + o + 3][c0 + 4];
            float o0 = ur.x + (d0[0] + 2.f*d1[0] + d2[0]) + (e2[0] - e0[0]);
            float o1 = ur.y + (d0[1] + 2.f*d1[1] + d2[1]) + (e2[1] - e0[1]);
            float o2 = ur.z + (d0[2] + 2.f*d1[2] + d2[2]) + (e2[2] - e0[2]);
            float o3 = ur.w + (d0[3] + 2.f*d1[3] + d2[3]) + (e2[3] - e0[3]);
            *(float4*)(oc + obase + (long)o * W) = make_float4(o0, o1, o2, o3);
        }
    }
}

__global__ __launch_bounds__(NT) void gcdd_fused(
    const float* __restrict__ u, float* __restrict__ out, int H, int W)
{
    __shared__ Smem s;
    const int tid = threadIdx.x;
    const int tx0 = blockIdx.x * TW;
    const int ty0 = blockIdx.y * TH;
    const long chan = blockIdx.z;
    const float* __restrict__ uc = u + chan * (long)H * W;
    float* __restrict__ oc = out + chan * (long)H * W;

    const bool inr = (tx0 >= 4) && (tx0 + TW + 4 <= W)
                  && (ty0 >= 3) && (ty0 + TH + 3 <= H);

    // ---- Stage 1: u tile -> LDS. 70 rows x 34 float4-groups ----
    for (int i = tid; i < SUH * 34; i += NT) {
        const int r = i / 34, g = i - r * 34;
        const int gy = ty0 + r - 3;
        const int gxb = tx0 + g * 4 - 4;
        float4 v;
        if (inr) {
            v = *(const float4*)(uc + (long)gy * W + gxb);
        } else {
            float e[4];
            #pragma unroll
            for (int k = 0; k < 4; ++k) {
                const int gx = gxb + k;
                const bool in = ((unsigned)gy < (unsigned)H) & ((unsigned)gx < (unsigned)W);
                e[k] = in ? uc[(long)gy * W + gx] : 0.f;
            }
            v = make_float4(e[0], e[1], e[2], e[3]);
        }
        *(float4*)&s.su[r][g * 4] = v;
    }
    __syncthreads();

    // ---- Stage 2: full register pipeline ----
    if (inr) compute_strip<false>(s, tid, tx0, ty0, oc, H, W);
    else     compute_strip<true >(s, tid, tx0, ty0, oc, H, W);
}

extern "C" void kernel_launch(void* const* d_in, const int* in_sizes, int n_in,
                              void* d_out, int out_size, void* d_ws, size_t ws_size,
                              hipStream_t stream) {
    const float* u = (const float*)d_in[0];
    float* out = (float*)d_out;

    const int H = 512, W = 512;
    const int channels = in_sizes[0] / (H * W);  // B*C = 48

    dim3 grid(W / TW, H / TH, channels);
    dim3 block(NT);
    gcdd_fused<<<grid, block, 0, stream>>>(u, out, H, W);
}